// Round 5
// baseline (1862.041 us; speedup 1.0000x reference)
//
#include <hip/hip_runtime.h>
#include <hip/hip_fp16.h>
#include <stdint.h>

static constexpr int N_NODES = 200000;
static constexpr int N_EDGES = 6400000;
static constexpr int F_INC = 128;
static constexpr int F1 = 12;
static constexpr int F2 = 24;
static constexpr int HS1_STRIDE = 16; // halfs -> 32 B rows
static constexpr int HS2_STRIDE = 32; // halfs -> 64 B rows
static constexpr int NBUCK = (N_NODES + 255) / 256; // 782
static constexpr int A1_CHUNK = 8192;   // x 782 blocks  (1024 thr)
static constexpr int A2_CHUNK = 16384;  // x 391 blocks  (1024 thr)

__device__ __forceinline__ int clampN(int v) {
    return min(max(v, 0), N_NODES - 1);
}

// ---- zero bucket counters ----
__global__ __launch_bounds__(1024) void zero_bcnt(int* __restrict__ bcnt) {
    int i = threadIdx.x;
    if (i < NBUCK) bcnt[i] = 0;
}

// ---- pass A1: bucket histogram (dest >> 8) ----
__global__ __launch_bounds__(1024) void bucket_count(const int* __restrict__ col,
                                                     int* __restrict__ bcnt) {
    __shared__ int h[NBUCK];
    for (int i = threadIdx.x; i < NBUCK; i += 1024) h[i] = 0;
    __syncthreads();
    int base = blockIdx.x * A1_CHUNK;
#pragma unroll
    for (int it = 0; it < A1_CHUNK / 1024; it++) {
        int e = base + it * 1024 + threadIdx.x;
        if (e < N_EDGES) atomicAdd(&h[clampN(col[e]) >> 8], 1);
    }
    __syncthreads();
    for (int i = threadIdx.x; i < NBUCK; i += 1024)
        if (h[i]) atomicAdd(&bcnt[i], h[i]);
}

// ---- pass S: scan bucket counts -> bbase (NBUCK+1), init bcur ----
__global__ __launch_bounds__(1024) void bucket_scan(const int* __restrict__ bcnt,
                                                    int* __restrict__ bbase,
                                                    int* __restrict__ bcur) {
    __shared__ int tmp[1024];
    int t = threadIdx.x;
    int v = (t < NBUCK) ? bcnt[t] : 0;
    tmp[t] = v;
    for (int off = 1; off < 1024; off <<= 1) {
        __syncthreads();
        int a = (t >= off) ? tmp[t - off] : 0;
        __syncthreads();
        tmp[t] += a;
    }
    __syncthreads();
    if (t < NBUCK) {
        int excl = tmp[t] - v;
        bbase[t] = excl;
        bcur[t] = excl;
    }
    if (t == 0) bbase[NBUCK] = N_EDGES;
}

// ---- pass A2: scatter packed (row<<8 | col&255) into bucket-grouped tmp ----
__global__ __launch_bounds__(1024) void bucket_scatter(const int* __restrict__ row,
                                                       const int* __restrict__ col,
                                                       int* __restrict__ bcur,
                                                       int* __restrict__ tmpArr) {
    __shared__ int h[NBUCK];
    __shared__ int curb[NBUCK];
    for (int i = threadIdx.x; i < NBUCK; i += 1024) h[i] = 0;
    __syncthreads();
    int base = blockIdx.x * A2_CHUNK;
#pragma unroll
    for (int it = 0; it < A2_CHUNK / 1024; it++) {
        int e = base + it * 1024 + threadIdx.x;
        if (e < N_EDGES) atomicAdd(&h[clampN(col[e]) >> 8], 1);
    }
    __syncthreads();
    for (int i = threadIdx.x; i < NBUCK; i += 1024) {
        int c = h[i];
        curb[i] = c ? atomicAdd(&bcur[i], c) : 0;
    }
    __syncthreads();
#pragma unroll
    for (int it = 0; it < A2_CHUNK / 1024; it++) {
        int e = base + it * 1024 + threadIdx.x;
        if (e < N_EDGES) {
            int c = clampN(col[e]);
            int r = clampN(row[e]);
            int b = c >> 8;
            int p = atomicAdd(&curb[b], 1);
            tmpArr[p] = (r << 8) | (c & 255);
        }
    }
}

// ---- per-bucket degree histogram -> dinv ----
__global__ __launch_bounds__(256) void bucket_deg(const int* __restrict__ tmpArr,
                                                  const int* __restrict__ bbase,
                                                  float* __restrict__ dinv) {
    __shared__ int h[256];
    int b = blockIdx.x;
    int t = threadIdx.x;
    int node0 = b << 8;
    int nn = min(256, N_NODES - node0);
    int s = bbase[b], e = bbase[b + 1];
    h[t] = 0;
    __syncthreads();
    for (int i = s + t; i < e; i += 256) atomicAdd(&h[tmpArr[i] & 255], 1);
    __syncthreads();
    if (t < nn) dinv[node0 + t] = rsqrtf((float)(h[t] + 1));
}

// ---- hs1[v] = (x[v] @ W1) * dinv[v], fp16, 32 B rows ----
__global__ __launch_bounds__(256) void gemm1(const float* __restrict__ x,
                                             const float* __restrict__ W1,
                                             const float* __restrict__ dinv,
                                             __half* __restrict__ hs1) {
    __shared__ float Wl[F_INC * F1];
    for (int i = threadIdx.x; i < F_INC * F1; i += 256) Wl[i] = W1[i];
    __syncthreads();
    int v = blockIdx.x * 256 + threadIdx.x;
    if (v >= N_NODES) return;
    float acc[F1];
#pragma unroll
    for (int f = 0; f < F1; f++) acc[f] = 0.f;
    const float4* xr = (const float4*)(x + (size_t)v * F_INC);
    for (int k4 = 0; k4 < F_INC / 4; k4++) {
        float4 xv = xr[k4];
        int kb = k4 * 4;
#pragma unroll
        for (int f = 0; f < F1; f++) {
            acc[f] += xv.x * Wl[(kb + 0) * F1 + f] + xv.y * Wl[(kb + 1) * F1 + f] +
                      xv.z * Wl[(kb + 2) * F1 + f] + xv.w * Wl[(kb + 3) * F1 + f];
        }
    }
    float dv = dinv[v];
    int w[6];
#pragma unroll
    for (int j = 0; j < 6; j++) {
        __half2 p = __floats2half2_rn(acc[2 * j] * dv, acc[2 * j + 1] * dv);
        w[j] = *(int*)&p;
    }
    __half* rowp = hs1 + (size_t)v * HS1_STRIDE;
    ((int4*)rowp)[0] = make_int4(w[0], w[1], w[2], w[3]);
    ((int2*)rowp)[2] = make_int2(w[4], w[5]);
}

__device__ __forceinline__ void unpack_row1(float* f, const __half* rowp) {
    int4 a = ((const int4*)rowp)[0];
    int2 b = ((const int2*)rowp)[2];
    int ws[6] = {a.x, a.y, a.z, a.w, b.x, b.y};
#pragma unroll
    for (int j = 0; j < 6; j++) {
        float2 t = __half22float2(*(__half2*)&ws[j]);
        f[2 * j] = t.x;
        f[2 * j + 1] = t.y;
    }
}

__device__ __forceinline__ void unpack_row2(float* f, const __half* rowp) {
    int4 a = ((const int4*)rowp)[0];
    int4 b = ((const int4*)rowp)[1];
    int4 c = ((const int4*)rowp)[2];
    int ws[12] = {a.x, a.y, a.z, a.w, b.x, b.y, b.z, b.w, c.x, c.y, c.z, c.w};
#pragma unroll
    for (int j = 0; j < 12; j++) {
        float2 t = __half22float2(*(__half2*)&ws[j]);
        f[2 * j] = t.x;
        f[2 * j + 1] = t.y;
    }
}

// ---- layer-1 aggregate (bucketed, LDS atomics) + relu + W2 -> hs2 (fp16) ----
__global__ __launch_bounds__(256) void agg1(const __half* __restrict__ hs1,
                                            const int* __restrict__ tmpArr,
                                            const int* __restrict__ bbase,
                                            const float* __restrict__ dinv,
                                            const float* __restrict__ W2,
                                            const float* __restrict__ b1,
                                            __half* __restrict__ hs2) {
    __shared__ float sacc[256 * F1]; // 12 KB
    __shared__ float Wl[F1 * F2];
    __shared__ float bl[F1];
    int t = threadIdx.x, b = blockIdx.x;
    for (int i = t; i < F1 * F2; i += 256) Wl[i] = W2[i];
    if (t < F1) bl[t] = b1[t];
#pragma unroll
    for (int k = 0; k < F1; k++) sacc[k * 256 + t] = 0.f;
    __syncthreads();
    int s = bbase[b], e = bbase[b + 1];
    for (int i = s + t; i < e; i += 256) {
        int en = tmpArr[i];
        int r = en >> 8, c = en & 255;
        float f[F1];
        unpack_row1(f, hs1 + (size_t)r * HS1_STRIDE);
        float* ap = &sacc[c * F1];
#pragma unroll
        for (int j = 0; j < F1; j++) atomicAdd(&ap[j], f[j]);
    }
    __syncthreads();
    int v = (b << 8) + t;
    if (v >= N_NODES) return;
    float acc[F1];
#pragma unroll
    for (int j = 0; j < F1; j++) acc[j] = sacc[t * F1 + j];
    float selfr[F1];
    unpack_row1(selfr, hs1 + (size_t)v * HS1_STRIDE);
#pragma unroll
    for (int j = 0; j < F1; j++) acc[j] += selfr[j];
    float dv = dinv[v];
    float o[F1];
#pragma unroll
    for (int f = 0; f < F1; f++) o[f] = fmaxf(dv * acc[f] + bl[f], 0.f);
    float h2[F2];
#pragma unroll
    for (int g = 0; g < F2; g++) {
        float sum = 0.f;
#pragma unroll
        for (int f = 0; f < F1; f++) sum += o[f] * Wl[f * F2 + g];
        h2[g] = dv * sum;
    }
    int w[12];
#pragma unroll
    for (int j = 0; j < 12; j++) {
        __half2 p = __floats2half2_rn(h2[2 * j], h2[2 * j + 1]);
        w[j] = *(int*)&p;
    }
    int4* op = (int4*)(hs2 + (size_t)v * HS2_STRIDE);
    op[0] = make_int4(w[0], w[1], w[2], w[3]);
    op[1] = make_int4(w[4], w[5], w[6], w[7]);
    op[2] = make_int4(w[8], w[9], w[10], w[11]);
}

// ---- layer-2 aggregate (bucketed, LDS atomics) + relu + fc1(relu) + fc2 -> logits ----
__global__ __launch_bounds__(256) void agg2(const __half* __restrict__ hs2,
                                            const int* __restrict__ tmpArr,
                                            const int* __restrict__ bbase,
                                            const float* __restrict__ dinv,
                                            const float* __restrict__ b2,
                                            const float* __restrict__ Wf1,
                                            const float* __restrict__ bf1,
                                            const float* __restrict__ Wf2,
                                            const float* __restrict__ bf2,
                                            float* __restrict__ out) {
    __shared__ float sacc[256 * F2]; // 24 KB
    __shared__ float W1s[F2 * 32];
    __shared__ float W2s[32 * 2];
    __shared__ float b2s[F2], b1s[32], bfs[2];
    int t = threadIdx.x, b = blockIdx.x;
    for (int i = t; i < F2 * 32; i += 256) W1s[i] = Wf1[i];
    if (t < 64) W2s[t] = Wf2[t];
    if (t < F2) b2s[t] = b2[t];
    if (t < 32) b1s[t] = bf1[t];
    if (t < 2) bfs[t] = bf2[t];
#pragma unroll
    for (int k = 0; k < F2; k++) sacc[k * 256 + t] = 0.f;
    __syncthreads();
    int s = bbase[b], e = bbase[b + 1];
    for (int i = s + t; i < e; i += 256) {
        int en = tmpArr[i];
        int r = en >> 8, c = en & 255;
        float f[F2];
        unpack_row2(f, hs2 + (size_t)r * HS2_STRIDE);
        float* ap = &sacc[c * F2];
#pragma unroll
        for (int j = 0; j < F2; j++) atomicAdd(&ap[j], f[j]);
    }
    __syncthreads();
    int v = (b << 8) + t;
    if (v >= N_NODES) return;
    float acc[F2];
#pragma unroll
    for (int j = 0; j < F2; j++) acc[j] = sacc[t * F2 + j];
    float selfr[F2];
    unpack_row2(selfr, hs2 + (size_t)v * HS2_STRIDE);
#pragma unroll
    for (int j = 0; j < F2; j++) acc[j] += selfr[j];
    float dv = dinv[v];
    float o2[F2];
#pragma unroll
    for (int f = 0; f < F2; f++) o2[f] = fmaxf(dv * acc[f] + b2s[f], 0.f);
    float c0 = bfs[0], c1 = bfs[1];
#pragma unroll
    for (int g = 0; g < 32; g++) {
        float sum = b1s[g];
#pragma unroll
        for (int f = 0; f < F2; f++) sum += o2[f] * W1s[f * 32 + g];
        sum = fmaxf(sum, 0.f);
        c0 += sum * W2s[2 * g + 0];
        c1 += sum * W2s[2 * g + 1];
    }
    float2 r; r.x = c0; r.y = c1;
    ((float2*)out)[v] = r;
}

extern "C" void kernel_launch(void* const* d_in, const int* in_sizes, int n_in,
                              void* d_out, int out_size, void* d_ws, size_t ws_size,
                              hipStream_t stream) {
    const float* x = (const float*)d_in[0];
    const int* erow = (const int*)d_in[1]; // edge_index delivered as int32
    const int* ecol = erow + N_EDGES;
    const float* W1 = (const float*)d_in[2];
    const float* b1 = (const float*)d_in[3];
    const float* W2 = (const float*)d_in[4];
    const float* b2 = (const float*)d_in[5];
    const float* Wf1 = (const float*)d_in[6];
    const float* bf1 = (const float*)d_in[7];
    const float* Wf2 = (const float*)d_in[8];
    const float* bf2 = (const float*)d_in[9];
    float* out = (float*)d_out;

    char* w = (char*)d_ws;
    auto alloc = [&](size_t bytes) -> char* {
        char* p = w;
        w += (bytes + 255) / 256 * 256;
        return p;
    };
    int* bcnt = (int*)alloc((size_t)NBUCK * 4);
    int* bbase = (int*)alloc((size_t)(NBUCK + 1) * 4);
    int* bcur = (int*)alloc((size_t)NBUCK * 4);
    float* dinv = (float*)alloc((size_t)N_NODES * 4);
    int* tmpArr = (int*)alloc((size_t)N_EDGES * 4);             // 25.6 MB, live to end
    __half* hs1 = (__half*)alloc((size_t)N_NODES * HS1_STRIDE * 2); // 6.4 MB
    __half* hs2 = (__half*)alloc((size_t)N_NODES * HS2_STRIDE * 2); // 12.8 MB

    const int nodeGrid = (N_NODES + 255) / 256;
    const int a1Grid = (N_EDGES + A1_CHUNK - 1) / A1_CHUNK; // 782
    const int a2Grid = (N_EDGES + A2_CHUNK - 1) / A2_CHUNK; // 391

    hipLaunchKernelGGL(zero_bcnt, dim3(1), dim3(1024), 0, stream, bcnt);
    hipLaunchKernelGGL(bucket_count, dim3(a1Grid), dim3(1024), 0, stream, ecol, bcnt);
    hipLaunchKernelGGL(bucket_scan, dim3(1), dim3(1024), 0, stream, bcnt, bbase, bcur);
    hipLaunchKernelGGL(bucket_scatter, dim3(a2Grid), dim3(1024), 0, stream, erow, ecol, bcur, tmpArr);
    hipLaunchKernelGGL(bucket_deg, dim3(NBUCK), dim3(256), 0, stream, tmpArr, bbase, dinv);
    hipLaunchKernelGGL(gemm1, dim3(nodeGrid), dim3(256), 0, stream, x, W1, dinv, hs1);
    hipLaunchKernelGGL(agg1, dim3(NBUCK), dim3(256), 0, stream,
                       hs1, tmpArr, bbase, dinv, W2, b1, hs2);
    hipLaunchKernelGGL(agg2, dim3(NBUCK), dim3(256), 0, stream,
                       hs2, tmpArr, bbase, dinv, b2, Wf1, bf1, Wf2, bf2, out);
}

// Round 6
// 662.195 us; speedup vs baseline: 2.8119x; 2.8119x over previous
//
#include <hip/hip_runtime.h>
#include <hip/hip_fp16.h>
#include <stdint.h>

static constexpr int N_NODES = 200000;
static constexpr int N_EDGES = 6400000;
static constexpr int F_INC = 128;
static constexpr int F1 = 12;
static constexpr int F2 = 24;
static constexpr int HS1_STRIDE = 16; // halfs -> 32 B rows
static constexpr int HS2_STRIDE = 32; // halfs -> 64 B rows
static constexpr int NBUCK = (N_NODES + 255) / 256; // 782
static constexpr int A1_CHUNK = 8192;   // 782 blocks (1024 thr)
static constexpr int A2_CHUNK = 16384;  // 391 blocks (1024 thr)

__device__ __forceinline__ int clampN(int v) {
    return min(max(v, 0), N_NODES - 1);
}

__global__ __launch_bounds__(1024) void zero_bcnt(int* __restrict__ bcnt) {
    int i = threadIdx.x;
    if (i < NBUCK) bcnt[i] = 0;
}

// ---- pass A1: bucket histogram (dest >> 8) ----
__global__ __launch_bounds__(1024) void bucket_count(const int* __restrict__ col,
                                                     int* __restrict__ bcnt) {
    __shared__ int h[NBUCK];
    for (int i = threadIdx.x; i < NBUCK; i += 1024) h[i] = 0;
    __syncthreads();
    int base = blockIdx.x * A1_CHUNK;
#pragma unroll
    for (int it = 0; it < A1_CHUNK / 1024; it++) {
        int e = base + it * 1024 + threadIdx.x;
        if (e < N_EDGES) atomicAdd(&h[clampN(col[e]) >> 8], 1);
    }
    __syncthreads();
    for (int i = threadIdx.x; i < NBUCK; i += 1024)
        if (h[i]) atomicAdd(&bcnt[i], h[i]);
}

// ---- pass S: scan bucket counts -> bbase (NBUCK+1), init bcur ----
__global__ __launch_bounds__(1024) void bucket_scan(const int* __restrict__ bcnt,
                                                    int* __restrict__ bbase,
                                                    int* __restrict__ bcur,
                                                    int* __restrict__ offs) {
    __shared__ int tmp[1024];
    int t = threadIdx.x;
    int v = (t < NBUCK) ? bcnt[t] : 0;
    tmp[t] = v;
    for (int off = 1; off < 1024; off <<= 1) {
        __syncthreads();
        int a = (t >= off) ? tmp[t - off] : 0;
        __syncthreads();
        tmp[t] += a;
    }
    __syncthreads();
    if (t < NBUCK) {
        int excl = tmp[t] - v;
        bbase[t] = excl;
        bcur[t] = excl;
    }
    if (t == 0) {
        bbase[NBUCK] = N_EDGES;
        offs[N_NODES] = N_EDGES;
    }
}

// ---- pass A2: scatter packed (row<<8 | col&255) into bucket-grouped tmp ----
__global__ __launch_bounds__(1024) void bucket_scatter(const int* __restrict__ row,
                                                       const int* __restrict__ col,
                                                       int* __restrict__ bcur,
                                                       int* __restrict__ tmpArr) {
    __shared__ int h[NBUCK];
    __shared__ int curb[NBUCK];
    for (int i = threadIdx.x; i < NBUCK; i += 1024) h[i] = 0;
    __syncthreads();
    int base = blockIdx.x * A2_CHUNK;
#pragma unroll
    for (int it = 0; it < A2_CHUNK / 1024; it++) {
        int e = base + it * 1024 + threadIdx.x;
        if (e < N_EDGES) atomicAdd(&h[clampN(col[e]) >> 8], 1);
    }
    __syncthreads();
    for (int i = threadIdx.x; i < NBUCK; i += 1024) {
        int c = h[i];
        curb[i] = c ? atomicAdd(&bcur[i], c) : 0;
    }
    __syncthreads();
#pragma unroll
    for (int it = 0; it < A2_CHUNK / 1024; it++) {
        int e = base + it * 1024 + threadIdx.x;
        if (e < N_EDGES) {
            int c = clampN(col[e]);
            int r = clampN(row[e]);
            int b = c >> 8;
            int p = atomicAdd(&curb[b], 1);
            tmpArr[p] = (r << 8) | (c & 255);
        }
    }
}

// ---- pass C: per-bucket degree hist -> offs/dinv + CSR fill via LDS cursors ----
__global__ __launch_bounds__(256) void bucket_fill(const int* __restrict__ tmpArr,
                                                   const int* __restrict__ bbase,
                                                   int* __restrict__ offs,
                                                   float* __restrict__ dinv,
                                                   int* __restrict__ csr) {
    __shared__ int h[256];
    __shared__ int sc[256];
    int b = blockIdx.x;
    int t = threadIdx.x;
    int node0 = b << 8;
    int nn = min(256, N_NODES - node0);
    int s = bbase[b], e = bbase[b + 1];
    h[t] = 0;
    __syncthreads();
    for (int i = s + t; i < e; i += 256) atomicAdd(&h[tmpArr[i] & 255], 1);
    __syncthreads();
    int deg = h[t];
    sc[t] = deg;
    for (int off = 1; off < 256; off <<= 1) {
        __syncthreads();
        int a = (t >= off) ? sc[t - off] : 0;
        __syncthreads();
        sc[t] += a;
    }
    __syncthreads();
    int excl = sc[t] - deg;
    if (t < nn) {
        offs[node0 + t] = s + excl;
        dinv[node0 + t] = rsqrtf((float)(deg + 1));
    }
    h[t] = s + excl; // reuse as cursor
    __syncthreads();
    for (int i = s + t; i < e; i += 256) {
        int en = tmpArr[i];
        int p = atomicAdd(&h[en & 255], 1);
        csr[p] = en >> 8;
    }
}

// ---- hs1[v] = (x[v] @ W1) * dinv[v], fp16, 32 B rows ----
__global__ __launch_bounds__(256) void gemm1(const float* __restrict__ x,
                                             const float* __restrict__ W1,
                                             const float* __restrict__ dinv,
                                             __half* __restrict__ hs1) {
    __shared__ float Wl[F_INC * F1];
    for (int i = threadIdx.x; i < F_INC * F1; i += 256) Wl[i] = W1[i];
    __syncthreads();
    int v = blockIdx.x * 256 + threadIdx.x;
    if (v >= N_NODES) return;
    float acc[F1];
#pragma unroll
    for (int f = 0; f < F1; f++) acc[f] = 0.f;
    const float4* xr = (const float4*)(x + (size_t)v * F_INC);
    for (int k4 = 0; k4 < F_INC / 4; k4++) {
        float4 xv = xr[k4];
        int kb = k4 * 4;
#pragma unroll
        for (int f = 0; f < F1; f++) {
            acc[f] += xv.x * Wl[(kb + 0) * F1 + f] + xv.y * Wl[(kb + 1) * F1 + f] +
                      xv.z * Wl[(kb + 2) * F1 + f] + xv.w * Wl[(kb + 3) * F1 + f];
        }
    }
    float dv = dinv[v];
    int w[6];
#pragma unroll
    for (int j = 0; j < 6; j++) {
        __half2 p = __floats2half2_rn(acc[2 * j] * dv, acc[2 * j + 1] * dv);
        w[j] = *(int*)&p;
    }
    __half* rowp = hs1 + (size_t)v * HS1_STRIDE;
    ((int4*)rowp)[0] = make_int4(w[0], w[1], w[2], w[3]);
    ((int2*)rowp)[2] = make_int2(w[4], w[5]);
}

__device__ __forceinline__ void acc_row1(float* acc, const __half* rowp) {
    int4 a = ((const int4*)rowp)[0];
    int2 b = ((const int2*)rowp)[2];
    int ws[6] = {a.x, a.y, a.z, a.w, b.x, b.y};
#pragma unroll
    for (int j = 0; j < 6; j++) {
        float2 t = __half22float2(*(__half2*)&ws[j]);
        acc[2 * j] += t.x;
        acc[2 * j + 1] += t.y;
    }
}

__device__ __forceinline__ void acc_row2(float* acc, const __half* rowp) {
    int4 a = ((const int4*)rowp)[0];
    int4 b = ((const int4*)rowp)[1];
    int4 c = ((const int4*)rowp)[2];
    int ws[12] = {a.x, a.y, a.z, a.w, b.x, b.y, b.z, b.w, c.x, c.y, c.z, c.w};
#pragma unroll
    for (int j = 0; j < 12; j++) {
        float2 t = __half22float2(*(__half2*)&ws[j]);
        acc[2 * j] += t.x;
        acc[2 * j + 1] += t.y;
    }
}

// ---- layer-1 aggregate + relu + W2 -> hs2 (fp16) ----
__global__ __launch_bounds__(256) void agg1_gemm2(const __half* __restrict__ hs1,
                                                  const int* __restrict__ offs,
                                                  const int* __restrict__ csr,
                                                  const float* __restrict__ dinv,
                                                  const float* __restrict__ W2,
                                                  const float* __restrict__ b1,
                                                  __half* __restrict__ hs2) {
    __shared__ float Wl[F1 * F2];
    __shared__ float bl[F1];
    for (int i = threadIdx.x; i < F1 * F2; i += 256) Wl[i] = W2[i];
    if (threadIdx.x < F1) bl[threadIdx.x] = b1[threadIdx.x];
    __syncthreads();
    int v = blockIdx.x * 256 + threadIdx.x;
    if (v >= N_NODES) return;
    float acc[F1];
#pragma unroll
    for (int f = 0; f < F1; f++) acc[f] = 0.f;
    acc_row1(acc, hs1 + (size_t)v * HS1_STRIDE);
    int s = offs[v], e = offs[v + 1];
    int i = s;
    for (; i + 4 <= e; i += 4) {
        int i0 = csr[i], i1 = csr[i + 1], i2 = csr[i + 2], i3 = csr[i + 3];
        acc_row1(acc, hs1 + (size_t)i0 * HS1_STRIDE);
        acc_row1(acc, hs1 + (size_t)i1 * HS1_STRIDE);
        acc_row1(acc, hs1 + (size_t)i2 * HS1_STRIDE);
        acc_row1(acc, hs1 + (size_t)i3 * HS1_STRIDE);
    }
    for (; i < e; i++)
        acc_row1(acc, hs1 + (size_t)csr[i] * HS1_STRIDE);
    float dv = dinv[v];
    float o[F1];
#pragma unroll
    for (int f = 0; f < F1; f++) o[f] = fmaxf(dv * acc[f] + bl[f], 0.f);
    float h2[F2];
#pragma unroll
    for (int g = 0; g < F2; g++) {
        float sum = 0.f;
#pragma unroll
        for (int f = 0; f < F1; f++) sum += o[f] * Wl[f * F2 + g];
        h2[g] = dv * sum;
    }
    int w[12];
#pragma unroll
    for (int j = 0; j < 12; j++) {
        __half2 p = __floats2half2_rn(h2[2 * j], h2[2 * j + 1]);
        w[j] = *(int*)&p;
    }
    int4* op = (int4*)(hs2 + (size_t)v * HS2_STRIDE);
    op[0] = make_int4(w[0], w[1], w[2], w[3]);
    op[1] = make_int4(w[4], w[5], w[6], w[7]);
    op[2] = make_int4(w[8], w[9], w[10], w[11]);
}

// ---- layer-2 aggregate + relu + fc1(relu) + fc2 -> logits ----
__global__ __launch_bounds__(256) void agg2_fc(const __half* __restrict__ hs2,
                                               const int* __restrict__ offs,
                                               const int* __restrict__ csr,
                                               const float* __restrict__ dinv,
                                               const float* __restrict__ b2,
                                               const float* __restrict__ Wf1,
                                               const float* __restrict__ bf1,
                                               const float* __restrict__ Wf2,
                                               const float* __restrict__ bf2,
                                               float* __restrict__ out) {
    __shared__ float W1s[F2 * 32];
    __shared__ float W2s[32 * 2];
    __shared__ float b2s[F2], b1s[32], bfs[2];
    for (int i = threadIdx.x; i < F2 * 32; i += 256) W1s[i] = Wf1[i];
    if (threadIdx.x < 64) W2s[threadIdx.x] = Wf2[threadIdx.x];
    if (threadIdx.x < F2) b2s[threadIdx.x] = b2[threadIdx.x];
    if (threadIdx.x < 32) b1s[threadIdx.x] = bf1[threadIdx.x];
    if (threadIdx.x < 2) bfs[threadIdx.x] = bf2[threadIdx.x];
    __syncthreads();
    int v = blockIdx.x * 256 + threadIdx.x;
    if (v >= N_NODES) return;
    float acc[F2];
#pragma unroll
    for (int f = 0; f < F2; f++) acc[f] = 0.f;
    acc_row2(acc, hs2 + (size_t)v * HS2_STRIDE);
    int s = offs[v], e = offs[v + 1];
    int i = s;
    for (; i + 4 <= e; i += 4) {
        int i0 = csr[i], i1 = csr[i + 1], i2 = csr[i + 2], i3 = csr[i + 3];
        acc_row2(acc, hs2 + (size_t)i0 * HS2_STRIDE);
        acc_row2(acc, hs2 + (size_t)i1 * HS2_STRIDE);
        acc_row2(acc, hs2 + (size_t)i2 * HS2_STRIDE);
        acc_row2(acc, hs2 + (size_t)i3 * HS2_STRIDE);
    }
    for (; i < e; i++)
        acc_row2(acc, hs2 + (size_t)csr[i] * HS2_STRIDE);
    float dv = dinv[v];
    float o2[F2];
#pragma unroll
    for (int f = 0; f < F2; f++) o2[f] = fmaxf(dv * acc[f] + b2s[f], 0.f);
    float c0 = bfs[0], c1 = bfs[1];
#pragma unroll
    for (int g = 0; g < 32; g++) {
        float sum = b1s[g];
#pragma unroll
        for (int f = 0; f < F2; f++) sum += o2[f] * W1s[f * 32 + g];
        sum = fmaxf(sum, 0.f);
        c0 += sum * W2s[2 * g + 0];
        c1 += sum * W2s[2 * g + 1];
    }
    float2 r; r.x = c0; r.y = c1;
    ((float2*)out)[v] = r;
}

extern "C" void kernel_launch(void* const* d_in, const int* in_sizes, int n_in,
                              void* d_out, int out_size, void* d_ws, size_t ws_size,
                              hipStream_t stream) {
    const float* x = (const float*)d_in[0];
    const int* erow = (const int*)d_in[1]; // edge_index delivered as int32
    const int* ecol = erow + N_EDGES;
    const float* W1 = (const float*)d_in[2];
    const float* b1 = (const float*)d_in[3];
    const float* W2 = (const float*)d_in[4];
    const float* b2 = (const float*)d_in[5];
    const float* Wf1 = (const float*)d_in[6];
    const float* bf1 = (const float*)d_in[7];
    const float* Wf2 = (const float*)d_in[8];
    const float* bf2 = (const float*)d_in[9];
    float* out = (float*)d_out;

    char* w = (char*)d_ws;
    auto alloc = [&](size_t bytes) -> char* {
        char* p = w;
        w += (bytes + 255) / 256 * 256;
        return p;
    };
    int* bcnt = (int*)alloc((size_t)NBUCK * 4);
    int* bbase = (int*)alloc((size_t)(NBUCK + 1) * 4);
    int* bcur = (int*)alloc((size_t)NBUCK * 4);
    int* offs = (int*)alloc((size_t)(N_NODES + 1) * 4);
    float* dinv = (float*)alloc((size_t)N_NODES * 4);
    int* csr = (int*)alloc((size_t)N_EDGES * 4);
    // union: tmpArr (25.6 MB) dead after bucket_fill; hs1 (6.4) + hs2 (12.8) after
    size_t hs1_bytes = (size_t)N_NODES * HS1_STRIDE * 2;
    size_t hs2_bytes = (size_t)N_NODES * HS2_STRIDE * 2;
    size_t uni_bytes = (size_t)N_EDGES * 4; // 25.6 MB >= hs1+hs2 (19.2 MB)
    char* uni = alloc(uni_bytes);
    int* tmpArr = (int*)uni;
    __half* hs1 = (__half*)uni;
    __half* hs2 = (__half*)(uni + hs1_bytes);

    const int nodeGrid = (N_NODES + 255) / 256;
    const int a1Grid = (N_EDGES + A1_CHUNK - 1) / A1_CHUNK; // 782
    const int a2Grid = (N_EDGES + A2_CHUNK - 1) / A2_CHUNK; // 391

    hipLaunchKernelGGL(zero_bcnt, dim3(1), dim3(1024), 0, stream, bcnt);
    hipLaunchKernelGGL(bucket_count, dim3(a1Grid), dim3(1024), 0, stream, ecol, bcnt);
    hipLaunchKernelGGL(bucket_scan, dim3(1), dim3(1024), 0, stream, bcnt, bbase, bcur, offs);
    hipLaunchKernelGGL(bucket_scatter, dim3(a2Grid), dim3(1024), 0, stream, erow, ecol, bcur, tmpArr);
    hipLaunchKernelGGL(bucket_fill, dim3(NBUCK), dim3(256), 0, stream, tmpArr, bbase, offs, dinv, csr);
    hipLaunchKernelGGL(gemm1, dim3(nodeGrid), dim3(256), 0, stream, x, W1, dinv, hs1);
    hipLaunchKernelGGL(agg1_gemm2, dim3(nodeGrid), dim3(256), 0, stream,
                       hs1, offs, csr, dinv, W2, b1, hs2);
    hipLaunchKernelGGL(agg2_fc, dim3(nodeGrid), dim3(256), 0, stream,
                       hs2, offs, csr, dinv, b2, Wf1, bf1, Wf2, bf2, out);
}

// Round 8
// 622.093 us; speedup vs baseline: 2.9932x; 1.0645x over previous
//
#include <hip/hip_runtime.h>
#include <hip/hip_fp16.h>
#include <stdint.h>

static constexpr int N_NODES = 200000;
static constexpr int N_EDGES = 6400000;
static constexpr int F_INC = 128;
static constexpr int F1 = 12;
static constexpr int F2 = 24;
static constexpr int HS1_STRIDE = 16; // halfs -> 32 B rows
static constexpr int HS2_STRIDE = 32; // halfs -> 64 B rows
static constexpr int NBUCK = (N_NODES + 255) / 256; // 782
static constexpr int NT = 7;          // source tiles of 32768 nodes (src >> 15)
static constexpr int KPB = 8;         // key slots per dest (7 tiles + 1 end)
static constexpr int A1_CHUNK = 8192;   // 782 blocks (1024 thr)
static constexpr int A2_CHUNK = 16384;  // 391 blocks (1024 thr)

__device__ __forceinline__ int clampN(int v) {
    return min(max(v, 0), N_NODES - 1);
}

__global__ __launch_bounds__(1024) void zero_bcnt(int* __restrict__ bcnt) {
    int i = threadIdx.x;
    if (i < NBUCK) bcnt[i] = 0;
}

// ---- pass A1: bucket histogram (dest >> 8) ----
__global__ __launch_bounds__(1024) void bucket_count(const int* __restrict__ col,
                                                     int* __restrict__ bcnt) {
    __shared__ int h[NBUCK];
    for (int i = threadIdx.x; i < NBUCK; i += 1024) h[i] = 0;
    __syncthreads();
    int base = blockIdx.x * A1_CHUNK;
#pragma unroll
    for (int it = 0; it < A1_CHUNK / 1024; it++) {
        int e = base + it * 1024 + threadIdx.x;
        if (e < N_EDGES) atomicAdd(&h[clampN(col[e]) >> 8], 1);
    }
    __syncthreads();
    for (int i = threadIdx.x; i < NBUCK; i += 1024)
        if (h[i]) atomicAdd(&bcnt[i], h[i]);
}

// ---- pass S: scan bucket counts -> bbase (NBUCK+1), init bcur ----
__global__ __launch_bounds__(1024) void bucket_scan(const int* __restrict__ bcnt,
                                                    int* __restrict__ bbase,
                                                    int* __restrict__ bcur) {
    __shared__ int tmp[1024];
    int t = threadIdx.x;
    int v = (t < NBUCK) ? bcnt[t] : 0;
    tmp[t] = v;
    for (int off = 1; off < 1024; off <<= 1) {
        __syncthreads();
        int a = (t >= off) ? tmp[t - off] : 0;
        __syncthreads();
        tmp[t] += a;
    }
    __syncthreads();
    if (t < NBUCK) {
        int excl = tmp[t] - v;
        bbase[t] = excl;
        bcur[t] = excl;
    }
    if (t == 0) bbase[NBUCK] = N_EDGES;
}

// ---- pass A2: scatter packed (row<<8 | col&255) into bucket-grouped tmp ----
__global__ __launch_bounds__(1024) void bucket_scatter(const int* __restrict__ row,
                                                       const int* __restrict__ col,
                                                       int* __restrict__ bcur,
                                                       int* __restrict__ tmpArr) {
    __shared__ int h[NBUCK];
    __shared__ int curb[NBUCK];
    for (int i = threadIdx.x; i < NBUCK; i += 1024) h[i] = 0;
    __syncthreads();
    int base = blockIdx.x * A2_CHUNK;
#pragma unroll
    for (int it = 0; it < A2_CHUNK / 1024; it++) {
        int e = base + it * 1024 + threadIdx.x;
        if (e < N_EDGES) atomicAdd(&h[clampN(col[e]) >> 8], 1);
    }
    __syncthreads();
    for (int i = threadIdx.x; i < NBUCK; i += 1024) {
        int c = h[i];
        curb[i] = c ? atomicAdd(&bcur[i], c) : 0;
    }
    __syncthreads();
#pragma unroll
    for (int it = 0; it < A2_CHUNK / 1024; it++) {
        int e = base + it * 1024 + threadIdx.x;
        if (e < N_EDGES) {
            int c = clampN(col[e]);
            int r = clampN(row[e]);
            int b = c >> 8;
            int p = atomicAdd(&curb[b], 1);
            tmpArr[p] = (r << 8) | (c & 255);
        }
    }
}

// ---- pass C: per-bucket counting sort by (dcol, src_tile) ----
__global__ __launch_bounds__(256) void bucket_fill(const int* __restrict__ tmpArr,
                                                   const int* __restrict__ bbase,
                                                   unsigned short* __restrict__ offs2,
                                                   float* __restrict__ dinv,
                                                   int* __restrict__ csr) {
    __shared__ int hist[256 * KPB]; // 8 KB
    __shared__ int part[256];
    int b = blockIdx.x, t = threadIdx.x;
    int node0 = b << 8;
    int s = bbase[b], e = bbase[b + 1];
    for (int k = t; k < 256 * KPB; k += 256) hist[k] = 0;
    __syncthreads();
    for (int i = s + t; i < e; i += 256) {
        int en = tmpArr[i];
        int key = ((en & 255) << 3) | ((en >> 8) >> 15);
        atomicAdd(&hist[key], 1);
    }
    __syncthreads();
    // thread t == dest t: serial exclusive scan of its 8 key slots
    int base = t << 3;
    int ex[KPB];
    int sum = 0;
#pragma unroll
    for (int j = 0; j < KPB; j++) { ex[j] = sum; sum += hist[base + j]; }
    part[t] = sum;
    int nn = min(256, N_NODES - node0);
    if (t < nn) dinv[node0 + t] = rsqrtf((float)(sum + 1));
    // block exclusive scan over part
    int mine = sum;
    for (int off = 1; off < 256; off <<= 1) {
        __syncthreads();
        int a = (t >= off) ? part[t - off] : 0;
        __syncthreads();
        part[t] += a;
    }
    __syncthreads();
    int chunk0 = part[t] - mine; // exclusive prefix for this dest
#pragma unroll
    for (int j = 0; j < KPB; j++) hist[base + j] = chunk0 + ex[j];
    __syncthreads();
    // offs2: bucket-local u16 starts (slot j = start of tile j; slot 7 = end)
    for (int k = t; k < 256 * KPB; k += 256)
        offs2[((size_t)b << 11) + k] = (unsigned short)hist[k];
    __syncthreads();
    // scatter: hist reused as cursors
    for (int i = s + t; i < e; i += 256) {
        int en = tmpArr[i];
        int src = en >> 8;
        int key = ((en & 255) << 3) | (src >> 15);
        int p = atomicAdd(&hist[key], 1);
        csr[s + p] = src;
    }
}

// ---- hs1[v] = (x[v] @ W1) * dinv[v], fp16, 32 B rows ----
__global__ __launch_bounds__(256) void gemm1(const float* __restrict__ x,
                                             const float* __restrict__ W1,
                                             const float* __restrict__ dinv,
                                             __half* __restrict__ hs1) {
    __shared__ float Wl[F_INC * F1];
    for (int i = threadIdx.x; i < F_INC * F1; i += 256) Wl[i] = W1[i];
    __syncthreads();
    int v = blockIdx.x * 256 + threadIdx.x;
    if (v >= N_NODES) return;
    float acc[F1];
#pragma unroll
    for (int f = 0; f < F1; f++) acc[f] = 0.f;
    const float4* xr = (const float4*)(x + (size_t)v * F_INC);
    for (int k4 = 0; k4 < F_INC / 4; k4++) {
        float4 xv = xr[k4];
        int kb = k4 * 4;
#pragma unroll
        for (int f = 0; f < F1; f++) {
            acc[f] += xv.x * Wl[(kb + 0) * F1 + f] + xv.y * Wl[(kb + 1) * F1 + f] +
                      xv.z * Wl[(kb + 2) * F1 + f] + xv.w * Wl[(kb + 3) * F1 + f];
        }
    }
    float dv = dinv[v];
    int w[6];
#pragma unroll
    for (int j = 0; j < 6; j++) {
        __half2 p = __floats2half2_rn(acc[2 * j] * dv, acc[2 * j + 1] * dv);
        w[j] = *(int*)&p;
    }
    __half* rowp = hs1 + (size_t)v * HS1_STRIDE;
    ((int4*)rowp)[0] = make_int4(w[0], w[1], w[2], w[3]);
    ((int2*)rowp)[2] = make_int2(w[4], w[5]);
}

__device__ __forceinline__ void acc_row1(float* acc, const __half* rowp) {
    int4 a = ((const int4*)rowp)[0];
    int2 b = ((const int2*)rowp)[2];
    int ws[6] = {a.x, a.y, a.z, a.w, b.x, b.y};
#pragma unroll
    for (int j = 0; j < 6; j++) {
        float2 t = __half22float2(*(__half2*)&ws[j]);
        acc[2 * j] += t.x;
        acc[2 * j + 1] += t.y;
    }
}

__device__ __forceinline__ void acc_row2(float* acc, const __half* rowp) {
    int4 a = ((const int4*)rowp)[0];
    int4 b = ((const int4*)rowp)[1];
    int4 c = ((const int4*)rowp)[2];
    int ws[12] = {a.x, a.y, a.z, a.w, b.x, b.y, b.z, b.w, c.x, c.y, c.z, c.w};
#pragma unroll
    for (int j = 0; j < 12; j++) {
        float2 t = __half22float2(*(__half2*)&ws[j]);
        acc[2 * j] += t.x;
        acc[2 * j + 1] += t.y;
    }
}

__device__ __forceinline__ void unpack_offsets(int* of, const unsigned short* offs2, int v) {
    const int4* p = (const int4*)(offs2 + ((size_t)v << 3));
    int4 a = p[0];
    of[0] = a.x & 0xffff; of[1] = (a.x >> 16) & 0xffff;
    of[2] = a.y & 0xffff; of[3] = (a.y >> 16) & 0xffff;
    of[4] = a.z & 0xffff; of[5] = (a.z >> 16) & 0xffff;
    of[6] = a.w & 0xffff; of[7] = (a.w >> 16) & 0xffff;
}

// ---- layer-1 aggregate (source-tiled) + relu + W2 -> hs2 (fp16) ----
__global__ __launch_bounds__(256) void agg1(const __half* __restrict__ hs1,
                                            const unsigned short* __restrict__ offs2,
                                            const int* __restrict__ csr,
                                            const int* __restrict__ bbase,
                                            const float* __restrict__ dinv,
                                            const float* __restrict__ W2,
                                            const float* __restrict__ b1,
                                            __half* __restrict__ hs2) {
    __shared__ float Wl[F1 * F2];
    __shared__ float bl[F1];
    int t = threadIdx.x, b = blockIdx.x;
    for (int i = t; i < F1 * F2; i += 256) Wl[i] = W2[i];
    if (t < F1) bl[t] = b1[t];
    __syncthreads();
    int v = (b << 8) + t;
    bool valid = v < N_NODES;
    int bb = bbase[b];
    float acc[F1];
#pragma unroll
    for (int f = 0; f < F1; f++) acc[f] = 0.f;
    if (valid) acc_row1(acc, hs1 + (size_t)v * HS1_STRIDE); // self loop
    int of[KPB];
    unpack_offsets(of, offs2, v);
    for (int tile = 0; tile < NT; tile++) {
        int i = bb + of[tile], e = bb + of[tile + 1];
        for (; i + 4 <= e; i += 4) {
            int i0 = csr[i], i1 = csr[i + 1], i2 = csr[i + 2], i3 = csr[i + 3];
            acc_row1(acc, hs1 + (size_t)i0 * HS1_STRIDE);
            acc_row1(acc, hs1 + (size_t)i1 * HS1_STRIDE);
            acc_row1(acc, hs1 + (size_t)i2 * HS1_STRIDE);
            acc_row1(acc, hs1 + (size_t)i3 * HS1_STRIDE);
        }
        for (; i < e; i++)
            acc_row1(acc, hs1 + (size_t)csr[i] * HS1_STRIDE);
        __syncthreads(); // keep block cohort tile-aligned for L2 reuse
    }
    if (!valid) return;
    float dv = dinv[v];
    float o[F1];
#pragma unroll
    for (int f = 0; f < F1; f++) o[f] = fmaxf(dv * acc[f] + bl[f], 0.f);
    float h2[F2];
#pragma unroll
    for (int g = 0; g < F2; g++) {
        float sum = 0.f;
#pragma unroll
        for (int f = 0; f < F1; f++) sum += o[f] * Wl[f * F2 + g];
        h2[g] = dv * sum;
    }
    int w[12];
#pragma unroll
    for (int j = 0; j < 12; j++) {
        __half2 p = __floats2half2_rn(h2[2 * j], h2[2 * j + 1]);
        w[j] = *(int*)&p;
    }
    int4* op = (int4*)(hs2 + (size_t)v * HS2_STRIDE);
    op[0] = make_int4(w[0], w[1], w[2], w[3]);
    op[1] = make_int4(w[4], w[5], w[6], w[7]);
    op[2] = make_int4(w[8], w[9], w[10], w[11]);
}

// ---- layer-2 aggregate (source-tiled) + relu + fc1(relu) + fc2 -> logits ----
__global__ __launch_bounds__(256) void agg2(const __half* __restrict__ hs2,
                                            const unsigned short* __restrict__ offs2,
                                            const int* __restrict__ csr,
                                            const int* __restrict__ bbase,
                                            const float* __restrict__ dinv,
                                            const float* __restrict__ b2,
                                            const float* __restrict__ Wf1,
                                            const float* __restrict__ bf1,
                                            const float* __restrict__ Wf2,
                                            const float* __restrict__ bf2,
                                            float* __restrict__ out) {
    __shared__ float W1s[F2 * 32];
    __shared__ float W2s[32 * 2];
    __shared__ float b2s[F2], b1s[32], bfs[2];
    int t = threadIdx.x, b = blockIdx.x;
    for (int i = t; i < F2 * 32; i += 256) W1s[i] = Wf1[i];
    if (t < 64) W2s[t] = Wf2[t];
    if (t < F2) b2s[t] = b2[t];
    if (t < 32) b1s[t] = bf1[t];
    if (t < 2) bfs[t] = bf2[t];
    __syncthreads();
    int v = (b << 8) + t;
    bool valid = v < N_NODES;
    int bb = bbase[b];
    float acc[F2];
#pragma unroll
    for (int f = 0; f < F2; f++) acc[f] = 0.f;
    if (valid) acc_row2(acc, hs2 + (size_t)v * HS2_STRIDE); // self loop
    int of[KPB];
    unpack_offsets(of, offs2, v);
    for (int tile = 0; tile < NT; tile++) {
        int i = bb + of[tile], e = bb + of[tile + 1];
        for (; i + 4 <= e; i += 4) {
            int i0 = csr[i], i1 = csr[i + 1], i2 = csr[i + 2], i3 = csr[i + 3];
            acc_row2(acc, hs2 + (size_t)i0 * HS2_STRIDE);
            acc_row2(acc, hs2 + (size_t)i1 * HS2_STRIDE);
            acc_row2(acc, hs2 + (size_t)i2 * HS2_STRIDE);
            acc_row2(acc, hs2 + (size_t)i3 * HS2_STRIDE);
        }
        for (; i < e; i++)
            acc_row2(acc, hs2 + (size_t)csr[i] * HS2_STRIDE);
        __syncthreads();
    }
    if (!valid) return;
    float dv = dinv[v];
    float o2[F2];
#pragma unroll
    for (int f = 0; f < F2; f++) o2[f] = fmaxf(dv * acc[f] + b2s[f], 0.f);
    float c0 = bfs[0], c1 = bfs[1];
#pragma unroll
    for (int g = 0; g < 32; g++) {
        float sum = b1s[g];
#pragma unroll
        for (int f = 0; f < F2; f++) sum += o2[f] * W1s[f * 32 + g];
        sum = fmaxf(sum, 0.f);
        c0 += sum * W2s[2 * g + 0];
        c1 += sum * W2s[2 * g + 1];
    }
    float2 r; r.x = c0; r.y = c1;
    ((float2*)out)[v] = r;
}

extern "C" void kernel_launch(void* const* d_in, const int* in_sizes, int n_in,
                              void* d_out, int out_size, void* d_ws, size_t ws_size,
                              hipStream_t stream) {
    const float* x = (const float*)d_in[0];
    const int* erow = (const int*)d_in[1]; // edge_index delivered as int32
    const int* ecol = erow + N_EDGES;
    const float* W1 = (const float*)d_in[2];
    const float* b1 = (const float*)d_in[3];
    const float* W2 = (const float*)d_in[4];
    const float* b2 = (const float*)d_in[5];
    const float* Wf1 = (const float*)d_in[6];
    const float* bf1 = (const float*)d_in[7];
    const float* Wf2 = (const float*)d_in[8];
    const float* bf2 = (const float*)d_in[9];
    float* out = (float*)d_out;

    char* w = (char*)d_ws;
    auto alloc = [&](size_t bytes) -> char* {
        char* p = w;
        w += (bytes + 255) / 256 * 256;
        return p;
    };
    int* bcnt = (int*)alloc((size_t)NBUCK * 4);
    int* bbase = (int*)alloc((size_t)(NBUCK + 1) * 4);
    int* bcur = (int*)alloc((size_t)NBUCK * 4);
    float* dinv = (float*)alloc((size_t)N_NODES * 4);
    unsigned short* offs2 = (unsigned short*)alloc((size_t)NBUCK * 256 * KPB * 2 + 256); // 3.2 MB (+pad)
    int* csr = (int*)alloc((size_t)N_EDGES * 4); // 25.6 MB
    // union: tmpArr (25.6 MB) dead after bucket_fill; hs1 (6.4) + hs2 (12.8) after
    size_t hs1_bytes = (size_t)N_NODES * HS1_STRIDE * 2;
    char* uni = alloc((size_t)N_EDGES * 4);
    int* tmpArr = (int*)uni;
    __half* hs1 = (__half*)uni;
    __half* hs2 = (__half*)(uni + hs1_bytes);

    const int nodeGrid = (N_NODES + 255) / 256;
    const int a1Grid = (N_EDGES + A1_CHUNK - 1) / A1_CHUNK; // 782
    const int a2Grid = (N_EDGES + A2_CHUNK - 1) / A2_CHUNK; // 391

    hipLaunchKernelGGL(zero_bcnt, dim3(1), dim3(1024), 0, stream, bcnt);
    hipLaunchKernelGGL(bucket_count, dim3(a1Grid), dim3(1024), 0, stream, ecol, bcnt);
    hipLaunchKernelGGL(bucket_scan, dim3(1), dim3(1024), 0, stream, bcnt, bbase, bcur);
    hipLaunchKernelGGL(bucket_scatter, dim3(a2Grid), dim3(1024), 0, stream, erow, ecol, bcur, tmpArr);
    hipLaunchKernelGGL(bucket_fill, dim3(NBUCK), dim3(256), 0, stream, tmpArr, bbase, offs2, dinv, csr);
    hipLaunchKernelGGL(gemm1, dim3(nodeGrid), dim3(256), 0, stream, x, W1, dinv, hs1);
    hipLaunchKernelGGL(agg1, dim3(NBUCK), dim3(256), 0, stream,
                       hs1, offs2, csr, bbase, dinv, W2, b1, hs2);
    hipLaunchKernelGGL(agg2, dim3(NBUCK), dim3(256), 0, stream,
                       hs2, offs2, csr, bbase, dinv, b2, Wf1, bf1, Wf2, bf2, out);
}